// Round 1
// baseline (588.969 us; speedup 1.0000x reference)
//
#include <hip/hip_runtime.h>

#define HH 192
#define WW 384
#define CC 16
#define OH 184
#define OW 376
#define NGRP 2
#define NTAP 25
#define TPX 10      // pixel-threads per block
#define PXPT 4      // pixels per thread
#define TILE_OX (TPX*PXPT)  // 40

// Kernel A: S[b][y][x] = sum_c volume[b][y][x][c]
__global__ void sumc_kernel(const float* __restrict__ vol, float* __restrict__ S, int n) {
    int idx = blockIdx.x * blockDim.x + threadIdx.x;
    if (idx >= n) return;
    const float4* p = reinterpret_cast<const float4*>(vol + (size_t)idx * CC);
    float4 a = p[0], b = p[1], c = p[2], d = p[3];
    float s = ((a.x + a.y) + (a.z + a.w)) + ((b.x + b.y) + (b.z + b.w))
            + ((c.x + c.y) + (c.z + c.w)) + ((d.x + d.y) + (d.z + d.w));
    S[idx] = s;
}

// Fused kernel: dilated 5x5 offset conv (implicit GEMM, fp32 VALU) + bilinear sampling.
// Block: 256 threads (250 active) = 25 taps x 10 pixel-threads; 40 pixels (ox) per block.
// Thread (tn=tap, tpx) accumulates float4 acc[px] = off[n=4*tap .. 4*tap+3] for 4 pixels,
// which is exactly {dy_g0, dy_g1, dx_g0, dx_g1} for its tap -> epilogue samples directly.
__global__ __launch_bounds__(256) void dconv_kernel(
    const float* __restrict__ vol, const float* __restrict__ w_off,
    const float* __restrict__ b_off, const float* __restrict__ S,
    float* __restrict__ out)
{
    const int tid = threadIdx.x;
    const int tn  = tid / TPX;   // tap 0..24
    const int tpx = tid % TPX;
    if (tn >= NTAP) return;

    const int tile = blockIdx.x;
    const int oy   = blockIdx.y;
    const int b    = blockIdx.z;
    const int ox_base = tile * TILE_OX;

    int ox[PXPT];
    int oxr[PXPT];
    #pragma unroll
    for (int i = 0; i < PXPT; ++i) {
        ox[i]  = ox_base + tpx + TPX * i;
        oxr[i] = ox[i] < OW ? ox[i] : (OW - 1);   // clamp; masked at store
    }

    // init accumulators with bias (n-quad of this tap)
    float4 bo = *reinterpret_cast<const float4*>(b_off + 4 * tn);
    float4 acc[PXPT];
    #pragma unroll
    for (int i = 0; i < PXPT; ++i) acc[i] = bo;

    const float* wbase = w_off + 4 * tn;   // + ((ky*5+kx)*CC + c)*100

    for (int ky = 0; ky < 5; ++ky) {
        const float* vrow = vol + (size_t)((b * HH + oy + 2 * ky) * WW) * CC;
        for (int kx = 0; kx < 5; ++kx) {
            const float* wkk = wbase + ((ky * 5 + kx) * CC) * 100;
            #pragma unroll
            for (int cq = 0; cq < 4; ++cq) {
                float4 w0 = *reinterpret_cast<const float4*>(wkk + (4 * cq + 0) * 100);
                float4 w1 = *reinterpret_cast<const float4*>(wkk + (4 * cq + 1) * 100);
                float4 w2 = *reinterpret_cast<const float4*>(wkk + (4 * cq + 2) * 100);
                float4 w3 = *reinterpret_cast<const float4*>(wkk + (4 * cq + 3) * 100);
                #pragma unroll
                for (int i = 0; i < PXPT; ++i) {
                    const float4 v = *reinterpret_cast<const float4*>(
                        vrow + (oxr[i] + 2 * kx) * CC + 4 * cq);
                    acc[i].x += v.x * w0.x + v.y * w1.x + v.z * w2.x + v.w * w3.x;
                    acc[i].y += v.x * w0.y + v.y * w1.y + v.z * w2.y + v.w * w3.y;
                    acc[i].z += v.x * w0.z + v.y * w1.z + v.z * w2.z + v.w * w3.z;
                    acc[i].w += v.x * w0.w + v.y * w1.w + v.z * w2.w + v.w * w3.w;
                }
            }
        }
    }

    // Sampling epilogue: tap = tn, groups g=0,1, 4 pixels.
    const int ky_t = tn / 5, kx_t = tn % 5;
    const float kv = (float)(2 * ky_t - 4);   // kys[tap/5]
    const float ku = (float)(2 * kx_t - 4);   // kxs[tap%5]
    const float byv = (float)(4 + oy);
    const float* Sb = S + (size_t)b * HH * WW;

    #pragma unroll
    for (int i = 0; i < PXPT; ++i) {
        if (ox[i] >= OW) continue;
        #pragma unroll
        for (int g = 0; g < NGRP; ++g) {
            float dy = (g == 0) ? acc[i].x : acc[i].y;
            float dx = (g == 0) ? acc[i].z : acc[i].w;
            float rx = kv + dy;      // pairs with W axis (reference quirk)
            float ry = ku + dx;      // pairs with H axis
            int x0 = (int)rx;        // trunc-toward-zero == astype(int32)
            int x1 = x0 + 1;
            int y0 = (int)ry;
            int y1 = y0 + 1;
            int x0c = min(max(x0, 0), WW - 1);
            int x1c = min(max(x1, 0), WW - 1);
            int y0c = min(max(y0, 0), HH - 1);
            int y1c = min(max(y1, 0), HH - 1);
            float fx0 = (float)x0c, fx1 = (float)x1c;
            float fy0 = (float)y0c, fy1 = (float)y1c;
            float w0v = (fy1 - ry) * (fx1 - rx);
            float w1v = (fy1 - byv) * (rx - fx0);
            float w2v = (ry - fy0) * (fx1 - rx);
            float w3v = (ry - fy0) * (rx - fx0);
            float s00 = Sb[y0c * WW + x0c];
            float s01 = Sb[y0c * WW + x1c];
            float s10 = Sb[y1c * WW + x0c];
            float s11 = Sb[y1c * WW + x1c];
            float o = w0v * s00 + w1v * s01 + w2v * s10 + w3v * s11;
            out[(size_t)(((b * NGRP + g) * OH + oy) * OW + ox[i]) * NTAP + tn] = o;
        }
    }
}

extern "C" void kernel_launch(void* const* d_in, const int* in_sizes, int n_in,
                              void* d_out, int out_size, void* d_ws, size_t ws_size,
                              hipStream_t stream) {
    const float* vol   = (const float*)d_in[0];
    const float* w_off = (const float*)d_in[1];
    const float* b_off = (const float*)d_in[2];
    float* out = (float*)d_out;
    float* S   = (float*)d_ws;              // 2*192*384 floats = 576 KiB

    const int nS = 2 * HH * WW;
    sumc_kernel<<<(nS + 255) / 256, 256, 0, stream>>>(vol, S, nS);

    dim3 grid((OW + TILE_OX - 1) / TILE_OX, OH, 2);   // 10 x 184 x 2
    dconv_kernel<<<grid, 256, 0, stream>>>(vol, w_off, b_off, S, out);
}